// Round 3
// baseline (146.758 us; speedup 1.0000x reference)
//
#include <hip/hip_runtime.h>
#include <hip/hip_bf16.h>

#define NROWS 65536
#define DIM   256
#define KC    512
#define ALPHA 0.05f

typedef __attribute__((ext_vector_type(8))) short bf16x8;
typedef __attribute__((ext_vector_type(4))) float f32x4;

static __device__ __forceinline__ unsigned short f2bf(float f) {
    union { __hip_bfloat16 h; unsigned short u; } c;
    c.h = __float2bfloat16(f);
    return c.u;
}

// Fragment-major center layout (identical to R1/R2 — verified correct):
// uint4 index = ((t16*8)+kk)*64 + l, t16 = center>>4, l = q*16+m holds
// center row t16*16+m, elems kk*32+q*8 .. +7.
__global__ void prep_centers(const float* __restrict__ centers,
                             float* __restrict__ csqh,
                             uint4* __restrict__ cbf2,
                             float* __restrict__ out) {
    const int t = threadIdx.x;
    const int r = blockIdx.x * 8 + (t >> 5);  // center row
    const int e = t & 31;                     // 8-elem group within row
    const float4* cv = reinterpret_cast<const float4*>(centers);
    float4 v0 = cv[r * 64 + e * 2];
    float4 v1 = cv[r * 64 + e * 2 + 1];
    float s = v0.x * v0.x + v0.y * v0.y + v0.z * v0.z + v0.w * v0.w
            + v1.x * v1.x + v1.y * v1.y + v1.z * v1.z + v1.w * v1.w;
    unsigned short o[8];
    o[0] = f2bf(v0.x); o[1] = f2bf(v0.y); o[2] = f2bf(v0.z); o[3] = f2bf(v0.w);
    o[4] = f2bf(v1.x); o[5] = f2bf(v1.y); o[6] = f2bf(v1.z); o[7] = f2bf(v1.w);
    const int t16 = r >> 4, m = r & 15;
    const int kk = e >> 2, q = e & 3, l = q * 16 + m;
    cbf2[(t16 * 8 + kk) * 64 + l] = *reinterpret_cast<uint4*>(o);
    #pragma unroll
    for (int off = 16; off; off >>= 1) s += __shfl_xor(s, off, 64);
    if (e == 0) csqh[r] = 0.5f * s;
    if (blockIdx.x == 0 && t == 0) out[0] = 0.f;
}

// Block: 64 rows. Wave w: row-group g=w>>1 (32 rows), col-half h=w&1 (256 cols).
// A resident in 64 VGPRs/wave; B streamed coalesced from L2; no LDS staging,
// one barrier total.
__global__ __launch_bounds__(256, 4) void kmeans_main(
    const float* __restrict__ emb,
    const uint4* __restrict__ cbf2,
    const float* __restrict__ csqh_g,
    float* __restrict__ out) {
    __shared__ float xsq_s[64];
    __shared__ float rowmax_s[2][64];

    const int t = threadIdx.x;
    const int w = t >> 6;
    const int lane = t & 63;
    const int m = lane & 15;
    const int q = lane >> 4;
    const int g = w >> 1;      // row-group 0/1
    const int h = w & 1;       // col-half 0/1
    const int r0 = blockIdx.x * 64 + g * 32;

    // ---- A fragments: fp32 global -> bf16 regs; exact fp32 xsq en route ----
    bf16x8 afr[2][8];
    float xp[2];
    #pragma unroll
    for (int rt = 0; rt < 2; ++rt) {
        float s = 0.f;
        const float* rowp = emb + (size_t)(r0 + rt * 16 + m) * DIM;
        #pragma unroll
        for (int kk = 0; kk < 8; ++kk) {
            const float4* p = reinterpret_cast<const float4*>(rowp + kk * 32 + q * 8);
            float4 v0 = p[0], v1 = p[1];
            s += v0.x * v0.x + v0.y * v0.y + v0.z * v0.z + v0.w * v0.w
               + v1.x * v1.x + v1.y * v1.y + v1.z * v1.z + v1.w * v1.w;
            bf16x8 a;
            a[0] = (short)f2bf(v0.x); a[1] = (short)f2bf(v0.y);
            a[2] = (short)f2bf(v0.z); a[3] = (short)f2bf(v0.w);
            a[4] = (short)f2bf(v1.x); a[5] = (short)f2bf(v1.y);
            a[6] = (short)f2bf(v1.z); a[7] = (short)f2bf(v1.w);
            afr[rt][kk] = a;
        }
        xp[rt] = s;
    }
    // row sum over the 4 q-lanes (xor 16, 32); q==0 lanes hold full x^2
    #pragma unroll
    for (int rt = 0; rt < 2; ++rt) {
        xp[rt] += __shfl_xor(xp[rt], 16, 64);
        xp[rt] += __shfl_xor(xp[rt], 32, 64);
        if (h == 0 && q == 0) xsq_s[g * 32 + rt * 16 + m] = xp[rt];
    }

    // ---- K-loop over this wave's 16 col-tiles (16 cols each) ----
    float maxv[2][4];
    #pragma unroll
    for (int rt = 0; rt < 2; ++rt)
        #pragma unroll
        for (int rg = 0; rg < 4; ++rg) maxv[rt][rg] = -1e30f;

    #pragma unroll 2
    for (int ct = 0; ct < 16; ++ct) {
        const int t16 = h * 16 + ct;
        const float ci = -csqh_g[t16 * 16 + m];   // -||c||^2/2 for col t16*16+m
        const uint4* bp = cbf2 + t16 * 8 * 64 + lane;

        f32x4 acc0 = {ci, ci, ci, ci};
        f32x4 acc1 = {ci, ci, ci, ci};
        // first half: kk 0..3
        bf16x8 bfr[4];
        #pragma unroll
        for (int kk = 0; kk < 4; ++kk)
            bfr[kk] = *reinterpret_cast<const bf16x8*>(bp + kk * 64);
        #pragma unroll
        for (int kk = 0; kk < 4; ++kk) {
            acc0 = __builtin_amdgcn_mfma_f32_16x16x32_bf16(afr[0][kk], bfr[kk], acc0, 0, 0, 0);
            acc1 = __builtin_amdgcn_mfma_f32_16x16x32_bf16(afr[1][kk], bfr[kk], acc1, 0, 0, 0);
        }
        // second half: kk 4..7
        #pragma unroll
        for (int kk = 0; kk < 4; ++kk)
            bfr[kk] = *reinterpret_cast<const bf16x8*>(bp + (kk + 4) * 64);
        #pragma unroll
        for (int kk = 0; kk < 4; ++kk) {
            acc0 = __builtin_amdgcn_mfma_f32_16x16x32_bf16(afr[0][kk + 4], bfr[kk], acc0, 0, 0, 0);
            acc1 = __builtin_amdgcn_mfma_f32_16x16x32_bf16(afr[1][kk + 4], bfr[kk], acc1, 0, 0, 0);
        }
        #pragma unroll
        for (int rg = 0; rg < 4; ++rg) {
            maxv[0][rg] = fmaxf(maxv[0][rg], acc0[rg]);
            maxv[1][rg] = fmaxf(maxv[1][rg], acc1[rg]);
        }
    }

    // ---- per-row max over this wave's 256 cols (xor over m-lanes) ----
    #pragma unroll
    for (int rt = 0; rt < 2; ++rt)
        #pragma unroll
        for (int rg = 0; rg < 4; ++rg) {
            float v = maxv[rt][rg];
            v = fmaxf(v, __shfl_xor(v, 1, 64));
            v = fmaxf(v, __shfl_xor(v, 2, 64));
            v = fmaxf(v, __shfl_xor(v, 4, 64));
            v = fmaxf(v, __shfl_xor(v, 8, 64));
            // C/D layout: row = rt*16 + q*4 + rg (col = m)  [m89/m91]
            if (m == 0) rowmax_s[h][g * 32 + rt * 16 + q * 4 + rg] = v;
        }
    __syncthreads();

    // ---- combine halves, d = sqrt(x^2 - 2*max(cross - c^2/2)), sum ----
    if (t < 64) {
        float M = fmaxf(rowmax_s[0][t], rowmax_s[1][t]);
        float d = sqrtf(fmaxf(xsq_s[t] - 2.f * M, 0.f));
        #pragma unroll
        for (int off = 1; off < 64; off <<= 1) d += __shfl_xor(d, off, 64);
        if (t == 0) atomicAdd(out, d * (ALPHA / (float)NROWS));
    }
}

extern "C" void kernel_launch(void* const* d_in, const int* in_sizes, int n_in,
                              void* d_out, int out_size, void* d_ws, size_t ws_size,
                              hipStream_t stream) {
    const float* emb     = (const float*)d_in[0];   // [65536, 256] fp32
    const float* centers = (const float*)d_in[1];   // [512, 256] fp32
    float* out = (float*)d_out;

    float* csqh = (float*)d_ws;                       // 512 * 4 B (= ||c||^2/2)
    uint4* cbf2 = (uint4*)((char*)d_ws + 2048);       // 256 KB fragment-major bf16

    prep_centers<<<dim3(KC / 8), dim3(256), 0, stream>>>(centers, csqh, cbf2, out);
    kmeans_main<<<dim3(NROWS / 64), dim3(256), 0, stream>>>(emb, cbf2, csqh, out);
}